// Round 9
// baseline (143.014 us; speedup 1.0000x reference)
//
#include <hip/hip_runtime.h>
#include <cstdint>

constexpr int Bv = 16, Nv = 4096, Fv = 512, Sv = 8, Kv = 1024, Dv = 64;
constexpr int Mv = Bv * Nv;  // 65536 rows
#define BDIM 256
constexpr int RG = 8;         // 16-row groups per wave -> 128 rows/wave, 512/block
constexpr int RING = 4;       // per-wave LDS tile ring depth (tiles of 16 cw)

using bf16x8 = __attribute__((ext_vector_type(8))) short;
using f32x4  = __attribute__((ext_vector_type(4))) float;
typedef unsigned short u16;
typedef unsigned int u32;

__device__ __forceinline__ u16 bf16rne(float f) {
  union { float f; u32 u; } v; v.f = f;
  u32 u = v.u + 0x7FFFu + ((v.u >> 16) & 1u);
  return (u16)(u >> 16);
}

__device__ __forceinline__ void gload_lds16(const void* g, void* lds) {
  __builtin_amdgcn_global_load_lds(
      (const __attribute__((address_space(1))) void*)g,
      (__attribute__((address_space(3))) void*)lds, 16, 0, 0);
}

// prep: cb fp32 -> swizzled bf16 codebook + c2m = -0.5*sum(c^2) (argmax form)
// swz layout: [s*1024+cw][slot'][8 bf16], slot' = slot ^ (cw&7)
__global__ void prep_kernel(const float* __restrict__ cb, u16* __restrict__ swz,
                            float* __restrict__ c2m) {
  int idx = blockIdx.x * BDIM + threadIdx.x;  // s*1024+cw
  int cw = idx & (Kv - 1);
  const float4* src = (const float4*)(cb + (size_t)idx * Dv);
  float v[64];
  float s2 = 0.f;
#pragma unroll
  for (int i = 0; i < 16; ++i) {
    float4 f = src[i];
    v[i * 4 + 0] = f.x; v[i * 4 + 1] = f.y; v[i * 4 + 2] = f.z; v[i * 4 + 3] = f.w;
    s2 += f.x * f.x + f.y * f.y + f.z * f.z + f.w * f.w;
  }
  c2m[idx] = -0.5f * s2;
  uint4* out = (uint4*)(swz + (size_t)idx * Dv);
#pragma unroll
  for (int slot = 0; slot < 8; ++slot) {
    int slotp = slot ^ (cw & 7);
    u32 w[4];
#pragma unroll
    for (int p = 0; p < 4; ++p)
      w[p] = (u32)bf16rne(v[slot * 8 + p * 2]) | ((u32)bf16rne(v[slot * 8 + p * 2 + 1]) << 16);
    uint4 pk; pk.x = w[0]; pk.y = w[1]; pk.z = w[2]; pk.w = w[3];
    out[slotp] = pk;
  }
}

// Kernel A: scores + argmax + dev partials ONLY (no quant write).
// block = 512 rows x 1 subspace, 4 independent waves, private 4-deep LDS rings,
// counted vmcnt(6), no main-loop barriers. score = <x,c> - 0.5*c2 via
// mfma(A=cb,B=x,C=c2m); lane-local argMAX with the 10-bit index OR'd into the
// score's low mantissa bits. Emits u16 best-index per (s,row).
__global__ __launch_bounds__(BDIM, 4) void pq_score(
    const float* __restrict__ x, const u16* __restrict__ swz,
    const float* __restrict__ c2m_g, u16* __restrict__ idxp,
    float* __restrict__ devpart) {
  __shared__ __attribute__((aligned(16))) u16 ring[4][RING][16 * Dv];  // 32KB
  __shared__ __attribute__((aligned(16))) float c2_lds[Kv];            // 4KB

  const int tid = threadIdx.x;
  const int s = blockIdx.y;
  const int row0 = blockIdx.x * (4 * RG * 16);
  const int wave = tid >> 6, lane = tid & 63;
  const int l15 = lane & 15, lg = lane >> 4;
  const int slotp0 = lg ^ (l15 & 7);        // swizzled 16B-slot for h=0
  const int slotp1 = (4 + lg) ^ (l15 & 7);  // h=1

  const u16* swz_s = swz + (size_t)s * Kv * Dv;

  // per-wave private staging of one 16-cw tile (2 x 1KB instrs)
  auto stage = [&](int t, int slot) {  // slot compile-time
    const u16* src = swz_s + (size_t)t * (16 * Dv) + lane * 8;
    gload_lds16(src, &ring[wave][slot][0]);
    gload_lds16(src + 512, &ring[wave][slot][512]);
  };

  // ---- prologue: c2 (cooperative) + tiles 0..2 into ring, then x->xf
  gload_lds16(c2m_g + s * Kv + tid * 4, &c2_lds[(tid & ~63) * 4]);
  stage(0, 0); stage(1, 1); stage(2, 2);

  bf16x8 xf[RG][2];
  float x2p[RG];
#pragma unroll
  for (int rg = 0; rg < RG; ++rg) {
    x2p[rg] = 0.f;
    const int row = row0 + wave * (RG * 16) + rg * 16 + l15;
    const float* xp = x + (size_t)row * Fv + s * Dv + lg * 8;
#pragma unroll
    for (int h = 0; h < 2; ++h) {
      float4 f0 = *(const float4*)(xp + h * 32);
      float4 f1 = *(const float4*)(xp + h * 32 + 4);
      x2p[rg] += f0.x * f0.x + f0.y * f0.y + f0.z * f0.z + f0.w * f0.w
               + f1.x * f1.x + f1.y * f1.y + f1.z * f1.z + f1.w * f1.w;
      bf16x8 v;
      v[0] = (short)bf16rne(f0.x); v[1] = (short)bf16rne(f0.y);
      v[2] = (short)bf16rne(f0.z); v[3] = (short)bf16rne(f0.w);
      v[4] = (short)bf16rne(f1.x); v[5] = (short)bf16rne(f1.y);
      v[6] = (short)bf16rne(f1.z); v[7] = (short)bf16rne(f1.w);
      xf[rg][h] = v;
    }
  }

  float bv[RG];
#pragma unroll
  for (int rg = 0; rg < RG; ++rg) bv[rg] = -3.0e38f;

  // one-time barrier: c2 visible to all waves (x consumption drained older vm)
  __syncthreads();

  // ---- per-tile compute: 2 ds_read + 16 MFMA + packed-index argmax (max3-shaped)
  auto tile = [&](int t, int slot) {  // slot compile-time
    const u16* base = &ring[wave][slot][0];
    bf16x8 a0 = *(const bf16x8*)(base + l15 * Dv + slotp0 * 8);
    bf16x8 a1 = *(const bf16x8*)(base + l15 * Dv + slotp1 * 8);
    f32x4 c2v = *(const f32x4*)&c2_lds[t * 16 + lg * 4];
    const u32 kb = (u32)(t * 16) | (u32)(lg * 4);
    const u32 k0 = kb, k1 = kb | 1u, k2 = kb | 2u, k3 = kb | 3u;  // hoisted
#pragma unroll
    for (int rg = 0; rg < RG; ++rg) {
      f32x4 acc = __builtin_amdgcn_mfma_f32_16x16x32_bf16(a0, xf[rg][0], c2v, 0, 0, 0);
      acc = __builtin_amdgcn_mfma_f32_16x16x32_bf16(a1, xf[rg][1], acc, 0, 0, 0);
      float p0 = __builtin_bit_cast(float, __builtin_bit_cast(u32, acc[0]) | k0);
      float p1 = __builtin_bit_cast(float, __builtin_bit_cast(u32, acc[1]) | k1);
      float p2 = __builtin_bit_cast(float, __builtin_bit_cast(u32, acc[2]) | k2);
      float p3 = __builtin_bit_cast(float, __builtin_bit_cast(u32, acc[3]) | k3);
      float m = fmaxf(fmaxf(p0, p1), p2);          // v_max3
      bv[rg] = fmaxf(fmaxf(m, p3), bv[rg]);        // v_max3
    }
  };

  // ---- main loop: phases 0..59 stage t+3 and compute t; counted vmcnt(6)
  // keeps 3 tiles (6 loads) in flight; never drains to 0 until the tail.
  for (int base = 0; base < 60; base += 4) {
#pragma unroll
    for (int p = 0; p < 4; ++p) {
      const int t = base + p;
      stage(t + 3, (p + 3) & 3);
      asm volatile("s_waitcnt vmcnt(6)" ::: "memory");
      tile(t, p & 3);
    }
  }
  stage(63, 3);
  asm volatile("s_waitcnt vmcnt(6)" ::: "memory");
  tile(60, 0);
  asm volatile("s_waitcnt vmcnt(4)" ::: "memory");
  tile(61, 1);
  asm volatile("s_waitcnt vmcnt(2)" ::: "memory");
  tile(62, 2);
  asm volatile("s_waitcnt vmcnt(0)" ::: "memory");
  tile(63, 3);

  // ---- cross-lane: max packed scores + sum x2 over the 4 lg groups
#pragma unroll
  for (int rg = 0; rg < RG; ++rg) {
    float b = bv[rg], xx = x2p[rg];
    b = fmaxf(b, __shfl_xor(b, 16, 64)); xx += __shfl_xor(xx, 16, 64);
    b = fmaxf(b, __shfl_xor(b, 32, 64)); xx += __shfl_xor(xx, 32, 64);
    bv[rg] = b; x2p[rg] = xx;
  }

  // dev partial: dist_row = x2 - 2*score_max (packed low bits ~1e-7, negligible)
  float dev = 0.f;
#pragma unroll
  for (int rg = 0; rg < RG; ++rg) dev += x2p[rg] - 2.f * bv[rg];
#pragma unroll
  for (int m = 1; m <= 8; m <<= 1) dev += __shfl_xor(dev, m, 64);
  if (lane == 0)
    devpart[((size_t)blockIdx.y * gridDim.x + blockIdx.x) * 4 + wave] = dev;

  // ---- best-index write: [s][row] u16 plane; lg==0 lanes, 16x2B contiguous/rg
  if (lg == 0) {
    u16* ip = idxp + (size_t)s * Mv + row0 + wave * (RG * 16) + l15;
#pragma unroll
    for (int rg = 0; rg < RG; ++rg)
      ip[rg * 16] = (u16)(__builtin_bit_cast(u32, bv[rg]) & 1023u);
  }
}

// Kernel B: pure streaming quant writer. Each thread = one 16B chunk of a row;
// 16-lane groups gather 256B contiguous from the L2-resident fp32 codebook and
// each block writes 4KB dense. 4-iter grid-stride.
__global__ __launch_bounds__(BDIM) void quant_write(
    const float* __restrict__ cb, const u16* __restrict__ idxp,
    float* __restrict__ quant) {
  const int nthread = 8192 * BDIM;
#pragma unroll
  for (int it = 0; it < 4; ++it) {
    int gid = (blockIdx.x * BDIM + threadIdx.x) + it * nthread;
    int row = gid >> 7;          // 128 chunks of 16B per 2KB row
    int c = gid & 127;
    int s = c >> 4;              // 16 chunks per subspace
    int d4 = c & 15;
    int k = idxp[(size_t)s * Mv + row];
    f32x4 v = *(const f32x4*)(cb + ((size_t)s * Kv + k) * Dv + d4 * 4);
    *(f32x4*)(quant + (size_t)row * Fv + c * 4) = v;
  }
}

// deterministic final reduction of 4096 wave partials -> dev scalar
__global__ void dev_reduce(const float* __restrict__ part, float* __restrict__ out) {
  __shared__ float sred[256];
  int tid = threadIdx.x;
  float s = 0.f;
  for (int i = tid; i < 4096; i += 256) s += part[i];
  sred[tid] = s;
  __syncthreads();
  for (int off = 128; off > 0; off >>= 1) {
    if (tid < off) sred[tid] += sred[tid + off];
    __syncthreads();
  }
  if (tid == 0) out[0] = sred[0] * (1.25f / 4194304.0f);
}

extern "C" void kernel_launch(void* const* d_in, const int* in_sizes, int n_in,
                              void* d_out, int out_size, void* d_ws, size_t ws_size,
                              hipStream_t stream) {
  const float* x = (const float*)d_in[0];   // (B,N,F) fp32
  const float* cb = (const float*)d_in[1];  // (S,K,D) fp32
  float* quant = (float*)d_out;
  float* dev = quant + (size_t)Mv * Fv;

  // ws: swz bf16 codebook (1MB), c2m (32KB), dev partials (16KB), idx plane (1MB)
  u16* swz = (u16*)d_ws;
  float* c2m = (float*)(swz + (size_t)Sv * Kv * Dv);
  float* part = c2m + Sv * Kv;
  u16* idxp = (u16*)(part + 4096);

  prep_kernel<<<(Sv * Kv) / BDIM, BDIM, 0, stream>>>(cb, swz, c2m);
  dim3 grid(Mv / 512, Sv);
  pq_score<<<grid, BDIM, 0, stream>>>(x, swz, c2m, idxp, part);
  quant_write<<<8192, BDIM, 0, stream>>>(cb, idxp, quant);
  dev_reduce<<<1, 256, 0, stream>>>(part, dev);
}

// Round 10
// 116.700 us; speedup vs baseline: 1.2255x; 1.2255x over previous
//
#include <hip/hip_runtime.h>
#include <cstdint>

constexpr int Bv = 16, Nv = 4096, Fv = 512, Sv = 8, Kv = 1024, Dv = 64;
constexpr int Mv = Bv * Nv;  // 65536 rows
#define BDIM 256
constexpr int RG = 4;         // 16-row groups per wave -> 64 rows/wave, 256/block

using bf16x8 = __attribute__((ext_vector_type(8))) short;
using f32x4  = __attribute__((ext_vector_type(4))) float;
typedef unsigned short u16;
typedef unsigned int u32;

__device__ __forceinline__ u16 bf16rne(float f) {
  union { float f; u32 u; } v; v.f = f;
  u32 u = v.u + 0x7FFFu + ((v.u >> 16) & 1u);
  return (u16)(u >> 16);
}

__device__ __forceinline__ void gload_lds16(const void* g, void* lds) {
  __builtin_amdgcn_global_load_lds(
      (const __attribute__((address_space(1))) void*)g,
      (__attribute__((address_space(3))) void*)lds, 16, 0, 0);
}

// prep: cb fp32 -> swizzled bf16 codebook + c2m = -0.5*sum(c^2) (argmax form)
// swz layout: [s*1024+cw][slot'][8 bf16], slot' = slot ^ (cw&7)
__global__ void prep_kernel(const float* __restrict__ cb, u16* __restrict__ swz,
                            float* __restrict__ c2m) {
  int idx = blockIdx.x * BDIM + threadIdx.x;  // s*1024+cw
  int cw = idx & (Kv - 1);
  const float4* src = (const float4*)(cb + (size_t)idx * Dv);
  float v[64];
  float s2 = 0.f;
#pragma unroll
  for (int i = 0; i < 16; ++i) {
    float4 f = src[i];
    v[i * 4 + 0] = f.x; v[i * 4 + 1] = f.y; v[i * 4 + 2] = f.z; v[i * 4 + 3] = f.w;
    s2 += f.x * f.x + f.y * f.y + f.z * f.z + f.w * f.w;
  }
  c2m[idx] = -0.5f * s2;
  uint4* out = (uint4*)(swz + (size_t)idx * Dv);
#pragma unroll
  for (int slot = 0; slot < 8; ++slot) {
    int slotp = slot ^ (cw & 7);
    u32 w[4];
#pragma unroll
    for (int p = 0; p < 4; ++p)
      w[p] = (u32)bf16rne(v[slot * 8 + p * 2]) | ((u32)bf16rne(v[slot * 8 + p * 2 + 1]) << 16);
    uint4 pk; pk.x = w[0]; pk.y = w[1]; pk.z = w[2]; pk.w = w[3];
    out[slotp] = pk;
  }
}

// main (fused): block = 256 rows x 1 subspace, 4 independent waves. Each wave
// streams 32 tiles of 32 codewords (4KB) through its PRIVATE 3-deep LDS ring
// (dist-2 prefetch, counted vmcnt(8), no main-loop barriers). 2048 blocks =
// ~2.7 generations/CU so prologue/epilogue bursts overlap other blocks' compute.
// score = <x,c> - 0.5*c2 via mfma(A=cb,B=x,C=c2m); lane-local argMAX with the
// 10-bit index OR'd into the score's low mantissa bits.
__global__ __launch_bounds__(BDIM, 4) void pq_mfma(
    const float* __restrict__ x, const float* __restrict__ cb,
    const u16* __restrict__ swz, const float* __restrict__ c2m_g,
    float* __restrict__ quant, float* __restrict__ devpart) {
  __shared__ __attribute__((aligned(16))) u16 ring[4][3][32 * Dv];  // 48KB
  __shared__ __attribute__((aligned(16))) float c2_lds[Kv];         // 4KB

  const int tid = threadIdx.x;
  const int s = blockIdx.y;
  const int row0 = blockIdx.x * 256;
  const int wave = tid >> 6, lane = tid & 63;
  const int l15 = lane & 15, lg = lane >> 4;
  const int slotp0 = lg ^ (l15 & 7);        // swizzled 16B-slot, h=0
  const int slotp1 = (4 + lg) ^ (l15 & 7);  // h=1

  const u16* swz_s = swz + (size_t)s * Kv * Dv;

  // per-wave private staging of one 32-cw tile (4 x 1KB)
  auto stage = [&](int t, int slot) {  // slot compile-time
    const u16* src = swz_s + (size_t)t * (32 * Dv) + lane * 8;
    u16* dst = &ring[wave][slot][0];
#pragma unroll
    for (int it = 0; it < 4; ++it)
      gload_lds16(src + it * 512, dst + it * 512);
  };

  // ---- prologue: c2 (cooperative, FIRST vmem) + tiles 0,1; then x->xf
  gload_lds16(c2m_g + s * Kv + tid * 4, &c2_lds[(tid & ~63) * 4]);
  stage(0, 0); stage(1, 1);

  bf16x8 xf[RG][2];
  float x2p[RG];
#pragma unroll
  for (int rg = 0; rg < RG; ++rg) {
    x2p[rg] = 0.f;
    const int row = row0 + wave * 64 + rg * 16 + l15;
    const float* xp = x + (size_t)row * Fv + s * Dv + lg * 8;
#pragma unroll
    for (int h = 0; h < 2; ++h) {
      float4 f0 = *(const float4*)(xp + h * 32);
      float4 f1 = *(const float4*)(xp + h * 32 + 4);
      x2p[rg] += f0.x * f0.x + f0.y * f0.y + f0.z * f0.z + f0.w * f0.w
               + f1.x * f1.x + f1.y * f1.y + f1.z * f1.z + f1.w * f1.w;
      bf16x8 v;
      v[0] = (short)bf16rne(f0.x); v[1] = (short)bf16rne(f0.y);
      v[2] = (short)bf16rne(f0.z); v[3] = (short)bf16rne(f0.w);
      v[4] = (short)bf16rne(f1.x); v[5] = (short)bf16rne(f1.y);
      v[6] = (short)bf16rne(f1.z); v[7] = (short)bf16rne(f1.w);
      xf[rg][h] = v;
    }
  }

  float bv[RG];
#pragma unroll
  for (int rg = 0; rg < RG; ++rg) bv[rg] = -3.0e38f;

  // c2 landed (everything but the 8 ring-loads drained), make visible to block
  asm volatile("s_waitcnt vmcnt(8)" ::: "memory");
  __builtin_amdgcn_s_barrier();

  // ---- per-tile compute: 4 ds_read_b128 + 16 MFMA + packed-index argmax
  auto tile = [&](int t, int slot) {  // slot compile-time
    const u16* base = &ring[wave][slot][0];
    bf16x8 a00 = *(const bf16x8*)(base + l15 * Dv + slotp0 * 8);
    bf16x8 a01 = *(const bf16x8*)(base + l15 * Dv + slotp1 * 8);
    bf16x8 a10 = *(const bf16x8*)(base + (16 + l15) * Dv + slotp0 * 8);
    bf16x8 a11 = *(const bf16x8*)(base + (16 + l15) * Dv + slotp1 * 8);
    f32x4 c2v0 = *(const f32x4*)&c2_lds[t * 32 + lg * 4];
    f32x4 c2v1 = *(const f32x4*)&c2_lds[t * 32 + 16 + lg * 4];
    const u32 kb0 = (u32)(t * 32) | (u32)(lg * 4);
    const u32 kb1 = kb0 | 16u;
    __builtin_amdgcn_s_setprio(1);
#pragma unroll
    for (int rg = 0; rg < RG; ++rg) {
      f32x4 acc = __builtin_amdgcn_mfma_f32_16x16x32_bf16(a00, xf[rg][0], c2v0, 0, 0, 0);
      acc = __builtin_amdgcn_mfma_f32_16x16x32_bf16(a01, xf[rg][1], acc, 0, 0, 0);
      f32x4 acd = __builtin_amdgcn_mfma_f32_16x16x32_bf16(a10, xf[rg][0], c2v1, 0, 0, 0);
      acd = __builtin_amdgcn_mfma_f32_16x16x32_bf16(a11, xf[rg][1], acd, 0, 0, 0);
      float p0 = __builtin_bit_cast(float, __builtin_bit_cast(u32, acc[0]) | kb0);
      float p1 = __builtin_bit_cast(float, __builtin_bit_cast(u32, acc[1]) | (kb0 | 1u));
      float p2 = __builtin_bit_cast(float, __builtin_bit_cast(u32, acc[2]) | (kb0 | 2u));
      float p3 = __builtin_bit_cast(float, __builtin_bit_cast(u32, acc[3]) | (kb0 | 3u));
      float q0 = __builtin_bit_cast(float, __builtin_bit_cast(u32, acd[0]) | kb1);
      float q1 = __builtin_bit_cast(float, __builtin_bit_cast(u32, acd[1]) | (kb1 | 1u));
      float q2 = __builtin_bit_cast(float, __builtin_bit_cast(u32, acd[2]) | (kb1 | 2u));
      float q3 = __builtin_bit_cast(float, __builtin_bit_cast(u32, acd[3]) | (kb1 | 3u));
      float m0 = fmaxf(fmaxf(p0, p1), p2);
      float m1 = fmaxf(fmaxf(p3, q0), q1);
      float m2 = fmaxf(fmaxf(q2, q3), bv[rg]);
      bv[rg] = fmaxf(fmaxf(m0, m1), m2);
    }
    __builtin_amdgcn_s_setprio(0);
  };

  // ---- main loop: 32 phases, slots period-3, dist-2 prefetch, vmcnt(8)
#pragma unroll 1
  for (int b = 0; b < 30; b += 3) {
    stage(b + 2, 2);
    asm volatile("s_waitcnt vmcnt(8)" ::: "memory");
    tile(b, 0);
    stage(b + 3, 0);
    asm volatile("s_waitcnt vmcnt(8)" ::: "memory");
    tile(b + 1, 1);
    stage(b + 4, 1);
    asm volatile("s_waitcnt vmcnt(8)" ::: "memory");
    tile(b + 2, 2);
  }
  asm volatile("s_waitcnt vmcnt(4)" ::: "memory");
  tile(30, 0);
  asm volatile("s_waitcnt vmcnt(0)" ::: "memory");
  tile(31, 1);

  // ---- cross-lane: max packed scores + sum x2 over the 4 lg groups
#pragma unroll
  for (int rg = 0; rg < RG; ++rg) {
    float b = bv[rg], xx = x2p[rg];
    b = fmaxf(b, __shfl_xor(b, 16, 64)); xx += __shfl_xor(xx, 16, 64);
    b = fmaxf(b, __shfl_xor(b, 32, 64)); xx += __shfl_xor(xx, 32, 64);
    bv[rg] = b; x2p[rg] = xx;
  }

  // dev partial: dist_row = x2 - 2*score_max (packed low bits ~1e-7, negligible)
  float dev = 0.f;
#pragma unroll
  for (int rg = 0; rg < RG; ++rg) dev += x2p[rg] - 2.f * bv[rg];
#pragma unroll
  for (int m = 1; m <= 8; m <<= 1) dev += __shfl_xor(dev, m, 64);
  if (lane == 0)
    devpart[((size_t)blockIdx.y * gridDim.x + blockIdx.x) * 4 + wave] = dev;

  // ---- coalesced quant gather: iter i covers rows i*4+lg; index shfl'd from
  // the lane holding that row; k = low 10 bits of packed max. 16-lane groups
  // write full 256B contiguous segments; nontemporal (write-once).
  const float* cbs = cb + (size_t)s * Kv * Dv;
  float* qbase = quant + (size_t)(row0 + wave * 64) * Fv + s * Dv;
#pragma unroll
  for (int i = 0; i < 16; ++i) {
    int rl = i * 4 + lg;
    int kk = __shfl(__builtin_bit_cast(int, bv[i >> 2]), 4 * (i & 3) + lg, 64) & 1023;
    f32x4 v = *(const f32x4*)(cbs + (size_t)kk * Dv + l15 * 4);
    __builtin_nontemporal_store(v, (f32x4*)(qbase + (size_t)rl * Fv + l15 * 4));
  }
}

// deterministic final reduction of 8192 wave partials -> dev scalar
__global__ void dev_reduce(const float* __restrict__ part, float* __restrict__ out) {
  __shared__ float sred[256];
  int tid = threadIdx.x;
  float s = 0.f;
  for (int i = tid; i < 8192; i += 256) s += part[i];
  sred[tid] = s;
  __syncthreads();
  for (int off = 128; off > 0; off >>= 1) {
    if (tid < off) sred[tid] += sred[tid + off];
    __syncthreads();
  }
  if (tid == 0) out[0] = sred[0] * (1.25f / 4194304.0f);
}

extern "C" void kernel_launch(void* const* d_in, const int* in_sizes, int n_in,
                              void* d_out, int out_size, void* d_ws, size_t ws_size,
                              hipStream_t stream) {
  const float* x = (const float*)d_in[0];   // (B,N,F) fp32
  const float* cb = (const float*)d_in[1];  // (S,K,D) fp32
  float* quant = (float*)d_out;
  float* dev = quant + (size_t)Mv * Fv;

  // ws: swz bf16 codebook (1MB), c2m (32KB), dev partials (32KB)
  u16* swz = (u16*)d_ws;
  float* c2m = (float*)(swz + (size_t)Sv * Kv * Dv);
  float* part = c2m + Sv * Kv;

  prep_kernel<<<(Sv * Kv) / BDIM, BDIM, 0, stream>>>(cb, swz, c2m);
  dim3 grid(Mv / 256, Sv);
  pq_mfma<<<grid, BDIM, 0, stream>>>(x, cb, swz, c2m, quant, part);
  dev_reduce<<<1, 256, 0, stream>>>(part, dev);
}